// Round 3
// baseline (386.614 us; speedup 1.0000x reference)
//
#include <hip/hip_runtime.h>
#include <math.h>

#define HW4   12544                 // (224*224)/4
#define BATCH 128
#define NUM_CLASSES 1000
#define N4    (BATCH * HW4)         // 1,605,632 float4-groups
#define TPB   256
#define CPB   (HW4 / TPB)           // 49 chunks per image (exact)
#define NCHUNKS (N4 / TPB)          // 6272 chunks of 256 float4-groups
#define PIXGRID 2048                // exactly 8 blocks/CU x 256 CUs resident
#define GRID  (PIXGRID + BATCH)     // 2176

typedef float v4f __attribute__((ext_vector_type(4)));

// <=64 VGPRs -> 8 waves/SIMD -> 32 waves/CU (the whole point of this round)
__launch_bounds__(TPB, 8)
__global__ void fused_loss_kernel(const v4f* __restrict__ objects,
                                  const v4f* __restrict__ locs,
                                  const v4f* __restrict__ gt,
                                  const float* __restrict__ scores,
                                  const int*   __restrict__ label,
                                  const float* __restrict__ obj_coor_p,
                                  const float* __restrict__ no_obj_confi_p,
                                  const float* __restrict__ img_class_weight_p,
                                  float* __restrict__ ws,
                                  float* __restrict__ out) {
    __shared__ float red[8];
    const int tid  = threadIdx.x;
    const int lane = tid & 63;
    const int wave = tid >> 6;

    if (blockIdx.x < BATCH) {
        // ---------------- class loss: one block per batch row ----------------
        const int b = blockIdx.x;
        const float* row = scores + b * NUM_CLASSES;

        float mx = -INFINITY;
        for (int i = tid; i < NUM_CLASSES; i += TPB)
            mx = fmaxf(mx, row[i]);
#pragma unroll
        for (int off = 32; off > 0; off >>= 1)
            mx = fmaxf(mx, __shfl_down(mx, off, 64));
        if (lane == 0) red[wave] = mx;
        __syncthreads();
        if (tid == 0)
            red[4] = fmaxf(fmaxf(red[0], red[1]), fmaxf(red[2], red[3]));
        __syncthreads();
        mx = red[4];

        float se = 0.0f;
        for (int i = tid; i < NUM_CLASSES; i += TPB)
            se += __expf(row[i] - mx);
#pragma unroll
        for (int off = 32; off > 0; off >>= 1)
            se += __shfl_down(se, off, 64);
        __syncthreads();
        if (lane == 0) red[wave] = se;
        __syncthreads();
        if (tid == 0) {
            float lse = mx + logf(red[0] + red[1] + red[2] + red[3]);
            atomicAdd(&ws[1], -(row[label[b]] - lse));
        }
    } else {
        // ------ pixel loss: round-0 burst structure at 32 waves/CU ----------
        const float coorW = *obj_coor_p;
        const float noW   = *no_obj_confi_p;
        float acc = 0.0f;

        // Grid-stride over chunks; chunks align to images (49/image), so all
        // stream pointers below are block-uniform -> SGPR bases; the only
        // per-lane address component is tid (one shared 32-bit voffset).
        for (unsigned c = (unsigned)(blockIdx.x - BATCH); c < NCHUNKS;
             c += PIXGRID) {
            const unsigned b  = c / CPB;
            const unsigned hw = (c - b * CPB) * TPB;            // block-uniform
            const v4f* gtp = gt      + (size_t)b * (5 * HW4) + hw;
            const v4f* lcp = locs    + (size_t)b * (4 * HW4) + hw;
            const v4f* obp = objects + (size_t)b * HW4 + hw;

            // ---- burst-issue all 10 dwordx4 loads ----
            v4f o  = obp[tid];
            v4f m  = gtp[tid];
            v4f g0 = gtp[1 * HW4 + tid];
            v4f g1 = gtp[2 * HW4 + tid];
            v4f g2 = gtp[3 * HW4 + tid];
            v4f g3 = gtp[4 * HW4 + tid];
            v4f l0 = lcp[0 * HW4 + tid];
            v4f l1 = lcp[1 * HW4 + tid];
            v4f l2 = lcp[2 * HW4 + tid];
            v4f l3 = lcp[3 * HW4 + tid];
            // Hard data-dependency fence: all 10 loads must issue before the
            // single s_waitcnt -> ~10 KB in flight per wave during the stall.
            asm volatile(""
                : "+v"(o), "+v"(m),
                  "+v"(g0), "+v"(g1), "+v"(g2), "+v"(g3),
                  "+v"(l0), "+v"(l1), "+v"(l2), "+v"(l3));

            // ---- branch-free compute ----
            v4f d0 = l0 - g0, d1 = l1 - g1, d2 = l2 - g2, d3 = l3 - g3;
            v4f sq = d0 * d0 + d1 * d1 + d2 * d2 + d3 * d3;
#pragma unroll
            for (int j = 0; j < 4; ++j) {
                const float p  = o[j];
                const float mm = m[j];                 // exactly 0.0f or 1.0f
                const float lognop = fmaxf(__logf(1.0f - p), -100.0f);
                const float logp   = fmaxf(__logf(p),        -100.0f);
                const float a  = -noW * lognop;              // m==0 contribution
                const float bb = fmaf(coorW, sq[j], -logp);  // m==1 contribution
                acc += fmaf(mm, bb - a, a);                  // a + m*(b-a)
            }
        }

        // ---- wave reduce, then cross-wave via LDS ----
#pragma unroll
        for (int off = 32; off > 0; off >>= 1)
            acc += __shfl_down(acc, off, 64);
        if (lane == 0) red[wave] = acc;
        __syncthreads();
        if (tid == 0)
            atomicAdd(&ws[0], red[0] + red[1] + red[2] + red[3]);
    }

    // ---------------- last-block finalize ----------------
    if (tid == 0) {
        __threadfence();                                  // publish our adds
        unsigned done = atomicAdd((unsigned int*)&ws[2], 1u);
        if (done == (unsigned)(GRID - 1)) {
            __threadfence();
            const float pix = atomicAdd(&ws[0], 0.0f);    // device-scope read
            const float cls = atomicAdd(&ws[1], 0.0f);
            out[0] = img_class_weight_p[0] * (cls / (float)BATCH)
                   + pix / (float)BATCH;
        }
    }
}

extern "C" void kernel_launch(void* const* d_in, const int* in_sizes, int n_in,
                              void* d_out, int out_size, void* d_ws, size_t ws_size,
                              hipStream_t stream) {
    const float* objects = (const float*)d_in[0];   // (B,H,W)
    const float* scores  = (const float*)d_in[1];   // (B,1000)
    const float* locs    = (const float*)d_in[2];   // (B,4,H,W)
    const int*   label   = (const int*)d_in[3];     // (B,)
    const float* gt      = (const float*)d_in[4];   // (B,5,H,W)
    const float* obj_coor         = (const float*)d_in[5];
    const float* no_obj_confi     = (const float*)d_in[6];
    const float* img_class_weight = (const float*)d_in[7];

    float* ws  = (float*)d_ws;                      // [0]=pix, [1]=cls, [2]=counter
    float* out = (float*)d_out;

    hipMemsetAsync(ws, 0, 3 * sizeof(float), stream);

    fused_loss_kernel<<<GRID, TPB, 0, stream>>>(
        (const v4f*)objects, (const v4f*)locs, (const v4f*)gt,
        scores, label, obj_coor, no_obj_confi, img_class_weight, ws, out);
}